// Round 1
// baseline (329.630 us; speedup 1.0000x reference)
//
#include <hip/hip_runtime.h>
#include <hip/hip_bf16.h>
#include <math.h>

#define SEQ 2048
#define DM 2048
#define NH 16
#define HD 128
#define QKV_N 6144

typedef __bf16 bf16;
typedef __bf16 bf16x8 __attribute__((ext_vector_type(8)));
typedef __bf16 bf16x4v __attribute__((ext_vector_type(4)));
typedef __bf16 bf16x2v __attribute__((ext_vector_type(2)));
typedef float f32x4 __attribute__((ext_vector_type(4)));

// 64-elem-row swizzle (8 chunk slots, 128B row = full bank revolution)
__device__ inline int sw_idx64(int row, int chunk) {
    return (row * 8 + (chunk ^ (row & 7))) * 8;
}
// 128-elem-row swizzle (16 chunk slots, 256B row)
__device__ inline int sw_idx128(int row, int chunk) {
    return (row * 16 + (chunk ^ (row & 15))) * 8;
}

__device__ inline void async16(const void* g, void* l) {
    __builtin_amdgcn_global_load_lds((const __attribute__((address_space(1))) void*)g,
                                     (__attribute__((address_space(3))) void*)l, 16, 0, 0);
}

// ---- weight transposes (z<4) + x fp32->bf16 convert (z==4) ----------------
__global__ void k_prep(const float* __restrict__ wq, const float* __restrict__ wk,
                       const float* __restrict__ wv, const float* __restrict__ wo,
                       bf16* __restrict__ wT, bf16* __restrict__ woT,
                       const float* __restrict__ x, bf16* __restrict__ xb) {
    const int z = blockIdx.z;
    int tx = threadIdx.x, ty = threadIdx.y;
    if (z == 4) {                                    // x convert: 1M float4s
        int bid = blockIdx.y * 64 + blockIdx.x;
        if (bid >= 1024) return;
        int i = bid * 1024 + ty * 32 + tx;
        float4 v = ((const float4*)x)[i];
        bf16x4v o;
        o.x = (bf16)v.x; o.y = (bf16)v.y; o.z = (bf16)v.z; o.w = (bf16)v.w;
        ((bf16x4v*)xb)[i] = o;
        return;
    }
    __shared__ float tile[32][33];
    const float* src = (z == 0) ? wq : (z == 1) ? wk : (z == 2) ? wv : wo;
    bf16* dst = (z < 3) ? (wT + (size_t)z * DM * DM) : woT;
    int bx = blockIdx.x * 32, by = blockIdx.y * 32;
    tile[ty][tx] = src[(size_t)(by + ty) * DM + bx + tx];
    __syncthreads();
    dst[(size_t)(bx + ty) * DM + by + tx] = (bf16)tile[tx][ty];
}

// ---- fused RoPE (in-place Q,K) + V transpose ------------------------------
__global__ void k_post(bf16* __restrict__ qkv, const float* __restrict__ cosT,
                       const float* __restrict__ sinT, bf16* __restrict__ vT) {
    __shared__ bf16 tile[32][33];
    int tx = threadIdx.x, ty = threadIdx.y;
    if (blockIdx.y < 64) {
        int bx = blockIdx.x * 32, by = blockIdx.y * 32;  // bx: channel, by: seq
        tile[ty][tx] = qkv[(size_t)(by + ty) * QKV_N + 2 * DM + bx + tx];
        __syncthreads();
        vT[(size_t)(bx + ty) * SEQ + by + tx] = tile[tx][ty];
    } else {
        int b = (blockIdx.y - 64) * 64 + blockIdx.x;     // 0..2047
        int idx = b * 1024 + ty * 32 + tx;               // 2M items
        int i = idx & 63;
        int h = (idx >> 6) & 15;
        int s = idx >> 10;
        float c = cosT[s * 64 + i], sn = sinT[s * 64 + i];
        size_t base = (size_t)s * QKV_N + h * HD + 2 * i;
        bf16x2v q = *(bf16x2v*)&qkv[base];
        float qr = (float)q.x, qi = (float)q.y;
        bf16x2v qo;
        qo.x = (bf16)(qr * c - qi * sn);
        qo.y = (bf16)(qr * sn + qi * c);
        *(bf16x2v*)&qkv[base] = qo;
        bf16x2v k = *(bf16x2v*)&qkv[base + DM];
        float kr = (float)k.x, ki = (float)k.y;
        bf16x2v ko;
        ko.x = (bf16)(kr * c - ki * sn);
        ko.y = (bf16)(kr * sn + ki * c);
        *(bf16x2v*)&qkv[base + DM] = ko;
    }
}

// ---- C[M][N] = A[M][K] * Bt[N][K]^T, 128 x BN tile, BK=64 -----------------
// (kept for the output projection GEMM)
template <typename OutT, int BN>
__global__ __launch_bounds__(256) void k_gemm_bt(const bf16* __restrict__ A,
                                                 const bf16* __restrict__ Bt,
                                                 OutT* __restrict__ C,
                                                 int M, int N, int K) {
    constexpr int NI = BN / 32;
    __shared__ bf16 As[128 * 64];
    __shared__ bf16 Bs[BN * 64];
    const int t = threadIdx.x;
    const int lane = t & 63;
    const int w = t >> 6;
    const int wr = (w >> 1) * 64, wc = (w & 1) * (BN / 2);
    const int l15 = lane & 15, quad = lane >> 4;
    const size_t bm = (size_t)blockIdx.y * 128, bn = (size_t)blockIdx.x * BN;
    f32x4 acc[4][NI];
#pragma unroll
    for (int i = 0; i < 4; ++i)
#pragma unroll
        for (int j = 0; j < NI; ++j) acc[i][j] = (f32x4){0.f, 0.f, 0.f, 0.f};

    for (int kt = 0; kt < K; kt += 64) {
#pragma unroll
        for (int j = 0; j < 4; ++j) {
            int c = j * 256 + t;
            int row = c >> 3, g = ((c & 7) ^ (row & 7)) * 8;
            async16(&A[(bm + row) * K + kt + g], &As[c * 8]);
        }
#pragma unroll
        for (int j = 0; j < NI; ++j) {
            int c = j * 256 + t;
            int row = c >> 3, g = ((c & 7) ^ (row & 7)) * 8;
            async16(&Bt[(bn + row) * K + kt + g], &Bs[c * 8]);
        }
        __syncthreads();
#pragma unroll
        for (int kh = 0; kh < 2; ++kh) {
            bf16x8 af[4], bfm[NI];
#pragma unroll
            for (int mi = 0; mi < 4; ++mi)
                af[mi] = *(const bf16x8*)&As[sw_idx64(wr + mi * 16 + l15, kh * 4 + quad)];
#pragma unroll
            for (int ni = 0; ni < NI; ++ni)
                bfm[ni] = *(const bf16x8*)&Bs[sw_idx64(wc + ni * 16 + l15, kh * 4 + quad)];
#pragma unroll
            for (int mi = 0; mi < 4; ++mi)
#pragma unroll
                for (int ni = 0; ni < NI; ++ni)
                    acc[mi][ni] = __builtin_amdgcn_mfma_f32_16x16x32_bf16(
                        af[mi], bfm[ni], acc[mi][ni], 0, 0, 0);
        }
        __syncthreads();
    }
#pragma unroll
    for (int mi = 0; mi < 4; ++mi)
#pragma unroll
        for (int ni = 0; ni < NI; ++ni)
#pragma unroll
            for (int r = 0; r < 4; ++r) {
                size_t row = bm + wr + mi * 16 + quad * 4 + r;
                size_t col = bn + wc + ni * 16 + l15;
                C[row * (size_t)N + col] = (OutT)acc[mi][ni][r];
            }
}

// ---- 256x256 8-wave GEMM, 4-phase K-loop, counted vmcnt (never drains) ----
// C[M][N] = A[M][K] * Bt[N][K]^T.  BK=64, 512 threads = 8 waves (2Mx4N),
// per-wave C = 128x64 (8x4 frags of 16x16).  LDS = 2 x (A 32KB + B 32KB).
// Staging for tile t+1 issued during tile t (4 A-loads at tile top, 2+2
// B-loads in phases 0/1); tile-start wait = vmcnt(4): retires exactly the
// previous tile's 8 loads, leaves the next tile's 4 in flight (T4).
// Raw s_barrier (no vmcnt drain) + mem fences; setprio around MFMA (T5).
template <typename OutT>
__global__ __launch_bounds__(512, 2) void k_gemm256(const bf16* __restrict__ A,
                                                    const bf16* __restrict__ Bt,
                                                    OutT* __restrict__ C,
                                                    int M, int N, int K) {
    __shared__ bf16 As[2 * 16384];
    __shared__ bf16 Bs[2 * 16384];
    const int t = threadIdx.x;
    const int lane = t & 63;
    const int w = t >> 6;
    const int wr = w >> 2, wc = w & 3;
    const int l15 = lane & 15, quad = lane >> 4;
    const size_t bm = (size_t)blockIdx.y * 256, bn = (size_t)blockIdx.x * 256;
    const int NT = K >> 6;

    // staging descriptors: 4 chunks for A + 4 for B per thread per K-tile.
    // dest is linear (global_load_lds requirement); source pre-swizzled so the
    // fragment read (sw_idx64) lands on the right data (involution).
    const bf16* pa[4];
    const bf16* pb[4];
    int cdst[4];
#pragma unroll
    for (int j = 0; j < 4; ++j) {
        int c = j * 512 + t;                         // 0..2047
        int row = c >> 3;
        int g = ((c & 7) ^ (row & 7)) * 8;
        cdst[j] = c * 8;
        pa[j] = A + (size_t)(bm + row) * K + g;
        pb[j] = Bt + (size_t)(bn + row) * K + g;
    }

    f32x4 acc[8][4];
#pragma unroll
    for (int i = 0; i < 8; ++i)
#pragma unroll
        for (int j = 0; j < 4; ++j) acc[i][j] = (f32x4){0.f, 0.f, 0.f, 0.f};

    // prologue: stage tile 0 into buffer 0
#pragma unroll
    for (int j = 0; j < 4; ++j) { async16(pa[j], &As[cdst[j]]); pa[j] += 64; }
#pragma unroll
    for (int j = 0; j < 4; ++j) { async16(pb[j], &Bs[cdst[j]]); pb[j] += 64; }

    for (int kt = 0; kt < NT; ++kt) {
        const int co = (kt & 1) ? 16384 : 0;         // compute buffer
        const int no = co ^ 16384;                   // staging buffer
        const bool pre = (kt + 1 < NT);
        // issue A-half of tile t+1 staging BEFORE the wait so vmcnt never
        // reaches 0 in the main loop (in-flight after wait: 4 loads).
        if (pre) {
#pragma unroll
            for (int j = 0; j < 4; ++j) { async16(pa[j], &As[no + cdst[j]]); pa[j] += 64; }
            asm volatile("s_waitcnt vmcnt(4)" ::: "memory");
        } else {
            asm volatile("s_waitcnt vmcnt(0)" ::: "memory");
        }
        __builtin_amdgcn_sched_barrier(0);
        __builtin_amdgcn_s_barrier();                // all waves' tile-t data in LDS
        asm volatile("" ::: "memory");               // no LDS read hoists above barrier

        bf16x8 a[4][2], b0[2][2], b1[2][2];

        // ---- phase 0: quadrant (mh=0, nh=0): 12 ds_reads + 2 stage + 16 MFMA
#pragma unroll
        for (int mi = 0; mi < 4; ++mi)
#pragma unroll
            for (int kh = 0; kh < 2; ++kh)
                a[mi][kh] = *(const bf16x8*)&As[co + sw_idx64(wr * 128 + mi * 16 + l15, kh * 4 + quad)];
#pragma unroll
        for (int ni = 0; ni < 2; ++ni)
#pragma unroll
            for (int kh = 0; kh < 2; ++kh)
                b0[ni][kh] = *(const bf16x8*)&Bs[co + sw_idx64(wc * 64 + ni * 16 + l15, kh * 4 + quad)];
        if (pre) {
            async16(pb[0], &Bs[no + cdst[0]]); pb[0] += 64;
            async16(pb[1], &Bs[no + cdst[1]]); pb[1] += 64;
        }
        __builtin_amdgcn_s_barrier();
        asm volatile("s_waitcnt lgkmcnt(0)" ::: "memory");
        __builtin_amdgcn_sched_barrier(0);
        __builtin_amdgcn_s_setprio(1);
#pragma unroll
        for (int mi = 0; mi < 4; ++mi)
#pragma unroll
            for (int ni = 0; ni < 2; ++ni)
#pragma unroll
                for (int kh = 0; kh < 2; ++kh)
                    acc[mi][ni] = __builtin_amdgcn_mfma_f32_16x16x32_bf16(
                        a[mi][kh], b0[ni][kh], acc[mi][ni], 0, 0, 0);
        __builtin_amdgcn_s_setprio(0);
        __builtin_amdgcn_s_barrier();
        asm volatile("" ::: "memory");

        // ---- phase 1: quadrant (mh=0, nh=1): 4 ds_reads + 2 stage + 16 MFMA
#pragma unroll
        for (int ni = 0; ni < 2; ++ni)
#pragma unroll
            for (int kh = 0; kh < 2; ++kh)
                b1[ni][kh] = *(const bf16x8*)&Bs[co + sw_idx64(wc * 64 + 32 + ni * 16 + l15, kh * 4 + quad)];
        if (pre) {
            async16(pb[2], &Bs[no + cdst[2]]); pb[2] += 64;
            async16(pb[3], &Bs[no + cdst[3]]); pb[3] += 64;
        }
        __builtin_amdgcn_s_barrier();
        asm volatile("s_waitcnt lgkmcnt(0)" ::: "memory");
        __builtin_amdgcn_sched_barrier(0);
        __builtin_amdgcn_s_setprio(1);
#pragma unroll
        for (int mi = 0; mi < 4; ++mi)
#pragma unroll
            for (int ni = 0; ni < 2; ++ni)
#pragma unroll
                for (int kh = 0; kh < 2; ++kh)
                    acc[mi][2 + ni] = __builtin_amdgcn_mfma_f32_16x16x32_bf16(
                        a[mi][kh], b1[ni][kh], acc[mi][2 + ni], 0, 0, 0);
        __builtin_amdgcn_s_setprio(0);
        __builtin_amdgcn_s_barrier();
        asm volatile("" ::: "memory");

        // ---- phase 2: quadrant (mh=1, nh=1): 8 ds_reads + 16 MFMA
#pragma unroll
        for (int mi = 0; mi < 4; ++mi)
#pragma unroll
            for (int kh = 0; kh < 2; ++kh)
                a[mi][kh] = *(const bf16x8*)&As[co + sw_idx64(wr * 128 + 64 + mi * 16 + l15, kh * 4 + quad)];
        __builtin_amdgcn_s_barrier();
        asm volatile("s_waitcnt lgkmcnt(0)" ::: "memory");
        __builtin_amdgcn_sched_barrier(0);
        __builtin_amdgcn_s_setprio(1);
#pragma unroll
        for (int mi = 0; mi < 4; ++mi)
#pragma unroll
            for (int ni = 0; ni < 2; ++ni)
#pragma unroll
                for (int kh = 0; kh < 2; ++kh)
                    acc[4 + mi][2 + ni] = __builtin_amdgcn_mfma_f32_16x16x32_bf16(
                        a[mi][kh], b1[ni][kh], acc[4 + mi][2 + ni], 0, 0, 0);
        __builtin_amdgcn_s_setprio(0);
        __builtin_amdgcn_s_barrier();
        asm volatile("" ::: "memory");

        // ---- phase 3: quadrant (mh=1, nh=0): pure MFMA (a fresh, b0 held)
        __builtin_amdgcn_s_setprio(1);
#pragma unroll
        for (int mi = 0; mi < 4; ++mi)
#pragma unroll
            for (int ni = 0; ni < 2; ++ni)
#pragma unroll
                for (int kh = 0; kh < 2; ++kh)
                    acc[4 + mi][ni] = __builtin_amdgcn_mfma_f32_16x16x32_bf16(
                        a[mi][kh], b0[ni][kh], acc[4 + mi][ni], 0, 0, 0);
        __builtin_amdgcn_s_setprio(0);
        __builtin_amdgcn_s_barrier();                // frees compute buffer for t+2 staging
        asm volatile("" ::: "memory");
    }

    // epilogue: same verified C/D mapping as k_gemm_bt
#pragma unroll
    for (int mi = 0; mi < 8; ++mi)
#pragma unroll
        for (int ni = 0; ni < 4; ++ni)
#pragma unroll
            for (int r = 0; r < 4; ++r) {
                size_t row = bm + wr * 128 + mi * 16 + quad * 4 + r;
                size_t col = bn + wc * 64 + ni * 16 + l15;
                C[row * (size_t)N + col] = (OutT)acc[mi][ni][r];
            }
}

// ---- causal flash attention, HD=128, 128-key tiles ------------------------
__global__ __launch_bounds__(256) void k_flash(const bf16* __restrict__ qkv,
                                               const bf16* __restrict__ vT,
                                               bf16* __restrict__ out) {
    __shared__ bf16 Ks[128 * 128];                   // [key][d] swizzled
    __shared__ bf16 Vs[128 * 128];                   // [ch][key] swizzled
    __shared__ bf16 Pl[4][16 * 128];                 // per-wave, swizzled
    const int t = threadIdx.x;
    const int lane = t & 63;
    const int w = t >> 6;
    const int l15 = lane & 15, quad = lane >> 4;
    const int b = blockIdx.x;
    const int h = (b & 7) * 2 + ((b >> 3) & 1);      // 2 heads per XCD slot
    const int qb = 31 - (b >> 4);                    // heavy first
    const int q0w = qb * 64 + w * 16;
    const float sc = 0.08838834764831845f;           // 1/sqrt(128)

    const size_t qrow = (size_t)(q0w + l15) * QKV_N + h * HD;
    bf16x8 aq[4];
#pragma unroll
    for (int u = 0; u < 4; ++u)
        aq[u] = *(const bf16x8*)&qkv[qrow + u * 32 + quad * 8];

    f32x4 o[8];
#pragma unroll
    for (int c = 0; c < 8; ++c) o[c] = (f32x4){0.f, 0.f, 0.f, 0.f};
    float l_r[4] = {0.f, 0.f, 0.f, 0.f};

    // staging: 2048 chunks per matrix, 8 per thread
    int srow[8], sg[8];
#pragma unroll
    for (int j = 0; j < 8; ++j) {
        int c = j * 256 + t;
        srow[j] = c >> 4;
        sg[j] = ((c & 15) ^ (srow[j] & 15)) * 8;
    }

    const int n128 = (qb + 2) >> 1;                  // 128-key tiles
    for (int kt = 0; kt < n128; ++kt) {
        const int kbase = kt * 128;
#pragma unroll
        for (int j = 0; j < 8; ++j)
            async16(&qkv[(size_t)(kbase + srow[j]) * QKV_N + DM + h * HD + sg[j]],
                    &Ks[(j * 256 + t) * 8]);
#pragma unroll
        for (int j = 0; j < 8; ++j)
            async16(&vT[(size_t)(h * HD + srow[j]) * SEQ + kbase + sg[j]],
                    &Vs[(j * 256 + t) * 8]);
        __syncthreads();
        // ---- QK^T: 8 key sub-tiles x 4 d-chunks ----
        f32x4 s[8];
#pragma unroll
        for (int sub = 0; sub < 8; ++sub) {
            f32x4 z = (f32x4){0.f, 0.f, 0.f, 0.f};
#pragma unroll
            for (int u = 0; u < 4; ++u) {
                bf16x8 kb = *(const bf16x8*)&Ks[sw_idx128(sub * 16 + l15, u * 4 + quad)];
                z = __builtin_amdgcn_mfma_f32_16x16x32_bf16(aq[u], kb, z, 0, 0, 0);
            }
            s[sub] = z;
        }
        const bool masked = (kt == n128 - 1);
#pragma unroll
        for (int sub = 0; sub < 8; ++sub)
#pragma unroll
            for (int r = 0; r < 4; ++r) {
                float p = __expf(s[sub][r] * sc);
                if (masked)
                    p = (kbase + sub * 16 + l15 <= q0w + quad * 4 + r) ? p : 0.f;
                l_r[r] += p;
                int rowp = quad * 4 + r;
                int col = sub * 16 + l15;
                Pl[w][rowp * 128 + ((col >> 3) ^ (rowp & 15)) * 8 + (col & 7)] = (bf16)p;
            }
        __asm__ __volatile__("s_waitcnt lgkmcnt(0)" ::: "memory");
        bf16x8 pf[4];
#pragma unroll
        for (int kk = 0; kk < 4; ++kk)
            pf[kk] = *(const bf16x8*)&Pl[w][sw_idx128(l15, kk * 4 + quad)];
#pragma unroll
        for (int c = 0; c < 8; ++c)
#pragma unroll
            for (int kk = 0; kk < 4; ++kk) {
                bf16x8 vb = *(const bf16x8*)&Vs[sw_idx128(c * 16 + l15, kk * 4 + quad)];
                o[c] = __builtin_amdgcn_mfma_f32_16x16x32_bf16(pf[kk], vb, o[c], 0, 0, 0);
            }
        __syncthreads();
    }

    float rl[4];
#pragma unroll
    for (int r = 0; r < 4; ++r) {
        float l = l_r[r];
        l += __shfl_xor(l, 1, 16);
        l += __shfl_xor(l, 2, 16);
        l += __shfl_xor(l, 4, 16);
        l += __shfl_xor(l, 8, 16);
        rl[r] = 1.0f / l;
    }
#pragma unroll
    for (int c = 0; c < 8; ++c)
#pragma unroll
        for (int r = 0; r < 4; ++r)
            out[(size_t)(q0w + quad * 4 + r) * DM + h * HD + c * 16 + l15] =
                (bf16)(o[c][r] * rl[r]);
}

extern "C" void kernel_launch(void* const* d_in, const int* in_sizes, int n_in,
                              void* d_out, int out_size, void* d_ws, size_t ws_size,
                              hipStream_t stream) {
    const float* x  = (const float*)d_in[0];
    const float* fc = (const float*)d_in[1];
    const float* fs = (const float*)d_in[2];
    // d_in[3] = mask (unused; causal mask applied analytically)
    const float* wq = (const float*)d_in[4];
    const float* wk = (const float*)d_in[5];
    const float* wv = (const float*)d_in[6];
    const float* wo = (const float*)d_in[7];
    float* out = (float*)d_out;

    char* ws = (char*)d_ws;
    bf16* xb  = (bf16*)(ws);                          //  8MB, reused as attn_out
    bf16* wT  = (bf16*)(ws + (size_t)(8u  << 20));    // 24MB  (wq|wk|wv transposed)
    bf16* woT = (bf16*)(ws + (size_t)(32u << 20));    //  8MB
    bf16* qkv = (bf16*)(ws + (size_t)(40u << 20));    // 24MB  [seq][6144]
    bf16* vT  = (bf16*)(ws + (size_t)(64u << 20));    //  8MB  [c][seq]

    k_prep<<<dim3(64, 64, 5), dim3(32, 32), 0, stream>>>(wq, wk, wv, wo, wT, woT, x, xb);
    k_gemm256<bf16><<<dim3(24, 8), 512, 0, stream>>>(xb, wT, qkv, SEQ, QKV_N, DM);
    k_post<<<dim3(64, 96), dim3(32, 32), 0, stream>>>(qkv, fc, fs, vT);
    k_flash<<<512, 256, 0, stream>>>(qkv, vT, xb);
    k_gemm_bt<float, 64><<<dim3(32, 16), 256, 0, stream>>>(xb, woT, out, SEQ, DM, DM);
}